// Round 13
// baseline (183.139 us; speedup 1.0000x reference)
//
#include <hip/hip_runtime.h>

#define BB 4
#define NN 16384
#define EE 65536
#define CC 256
#define MM 64

// ws float offsets
#define WS_NORM   0                  // B*M (atomics, memset each launch)
#define WS_T1     256
#define WS_ESN    512
#define WS_BCOMB  768                // 64
#define WS_ITX    832                // 64
#define WS_ITE    896                // 64
#define WS_WES2   1024               // 64*64 = 4096  (itE ⊙ W_eslice)
#define WS_WCOMB  5120               // C*M = 16384
#define WS_SW2    21504              // bf16 SW2 [B*N*M ushorts] lives here (8MB);
#define WS_SSUM   WS_SW2             // after kE, overlaid by Ssum [B*M*C floats]
#define WS_SPART  4215808            // B*PB*M*C partials

static __device__ __forceinline__ unsigned short f2bf(float f) {
    unsigned int u = __float_as_uint(f);
    unsigned int r = (u + 0x7FFFu + ((u >> 16) & 1u)) >> 16;   // RNE
    return (unsigned short)r;
}

// async global->LDS, 16B per lane; lds dest = wave-uniform base + lane*16
static __device__ __forceinline__ void gl_lds16(const float* g, float* l) {
    __builtin_amdgcn_global_load_lds(
        (const __attribute__((address_space(1))) void*)g,
        (__attribute__((address_space(3))) void*)l, 16, 0, 0);
}

// ---------- P: W_comb = W_x @ W_slice ----------
__global__ __launch_bounds__(256) void kP(const float* __restrict__ Wx,
                                          const float* __restrict__ Wsl,
                                          float* __restrict__ ws) {
    int e = blockIdx.x * 256 + threadIdx.x;   // 16384 entries
    int c = e >> 6, m = e & 63;
    float acc = 0.f;
    for (int k = 0; k < CC; ++k) acc += Wx[c * CC + k] * Wsl[k * MM + m];
    ws[WS_WCOMB + e] = acc;
}

// ---------- P2: b_comb, inverse temps, Wes2 = itE ⊙ Wes ----------
__global__ void kP2(const float* __restrict__ bx, const float* __restrict__ phx,
                    const float* __restrict__ Wsl, const float* __restrict__ bsl,
                    const float* __restrict__ tx, const float* __restrict__ te,
                    const float* __restrict__ Wes,
                    float* __restrict__ ws) {
    int m = threadIdx.x; // 64 threads
    float acc = bsl[m];
    for (int k = 0; k < CC; ++k) acc += (bx[k] + phx[k]) * Wsl[k * MM + m];
    ws[WS_BCOMB + m] = acc;
    ws[WS_ITX + m] = 1.f / fminf(fmaxf(tx[m], 0.01f), 5.f);
    ws[WS_ITE + m] = 1.f / fminf(fmaxf(te[m], 0.01f), 5.f);
    for (int k = 0; k < 64; ++k) {
        float itk = 1.f / fminf(fmaxf(te[k], 0.01f), 5.f);
        ws[WS_WES2 + k * 64 + m] = itk * Wes[k * 64 + m];
    }
}

// ---------- N1: x@W_comb -> softmax -> sw (out1) + norm + fused sw@Wes2 -> sw2b ----------
// r13: main loop staged via async global_load_lds (zero VGPR prefetch), double
// buffered: issue DMA for chunk c+1, compute chunk c, __syncthreads drains.
// LDS dest is linear (no pad) -> stride-32 read conflict fixed by pre-swizzling
// the GLOBAL source column (slot s holds col s^(r&7)); read slot cc4^(r&7) = 2-way.
// Epilogue (r12 proven): LDS round-trip swl + Wes2, no shfl.
__global__ __launch_bounds__(256, 2) void kN1(const float* __restrict__ x,
                                              const float* __restrict__ ws,
                                              float* __restrict__ out1,
                                              unsigned short* __restrict__ sw2b,
                                              float* __restrict__ norm_acc) {
    // main: xs0=smem[0..4095], xs1=[4096..8191], Wst0=[8192..10239], Wst1=[10240..12287]
    // epi:  We2=smem[0..4095], swl=smem[4096..12799] (128x68)
    __shared__ float smem[12800];    // 51.2 KB
    __shared__ float redn[4][64];
    __shared__ float bcs[64], itxs[64];
    const int tid = threadIdx.x;
    const int lane = tid & 63, wv = tid >> 6;
    const int row0 = blockIdx.x * 128;
    const int b = blockIdx.x >> 7;   // 128 blocks per batch
    const int r = tid >> 2;          // 0..63 (rows r and r+64)
    const int h = tid & 3;           // m-quarter
    const float* Wc = ws + WS_WCOMB;

    if (tid < 64) { bcs[tid] = ws[WS_BCOMB + tid]; itxs[tid] = ws[WS_ITX + tid]; }

    // stage chunk c0 into xb (x, swizzled source) and wb (W, linear)
    const int srow = lane >> 3, sslot = lane & 7;      // x-stage coords
#define STAGE_CHUNK(c0_, xb_, wb_)                                              \
    {                                                                           \
        _Pragma("unroll")                                                       \
        for (int j = 0; j < 4; ++j) {                                           \
            int rb = wv * 32 + j * 8;                                           \
            const float* src = x + (size_t)(row0 + rb + srow) * CC + (c0_)      \
                               + ((sslot ^ srow) << 2);                         \
            gl_lds16(src, (xb_) + rb * 32);                                     \
        }                                                                       \
        _Pragma("unroll")                                                       \
        for (int j = 0; j < 2; ++j) {                                           \
            int f = (wv * 2 + j) * 64 + lane;                                   \
            gl_lds16(Wc + (c0_) * MM + f * 4, (wb_) + (wv * 2 + j) * 256);      \
        }                                                                       \
    }

    float acc[2][16];
#pragma unroll
    for (int i = 0; i < 2; ++i)
#pragma unroll
        for (int j = 0; j < 16; ++j) acc[i][j] = 0.f;

    STAGE_CHUNK(0, smem, smem + 8192);
    __syncthreads();

    for (int ci = 0; ci < 8; ++ci) {
        float* xsb = smem + (ci & 1) * 4096;
        float* wsb = smem + 8192 + (ci & 1) * 2048;
        if (ci < 7)
            STAGE_CHUNK((ci + 1) * 32, smem + ((ci + 1) & 1) * 4096,
                        smem + 8192 + ((ci + 1) & 1) * 2048);
#pragma unroll
        for (int cc4 = 0; cc4 < 8; ++cc4) {
            int slot4 = (cc4 ^ (r & 7)) << 2;
            float4 a0 = *(float4*)&xsb[(r     ) * 32 + slot4];
            float4 a1 = *(float4*)&xsb[(r + 64) * 32 + slot4];
            float av0[4] = {a0.x, a0.y, a0.z, a0.w};
            float av1[4] = {a1.x, a1.y, a1.z, a1.w};
#pragma unroll
            for (int k = 0; k < 4; ++k) {
                float xv0 = av0[k], xv1 = av1[k];
                const float4* wrow = (const float4*)&wsb[(cc4 * 4 + k) * 64 + h * 16];
#pragma unroll
                for (int q = 0; q < 4; ++q) {
                    float4 w = wrow[q];
                    acc[0][q * 4 + 0] += xv0 * w.x; acc[0][q * 4 + 1] += xv0 * w.y;
                    acc[0][q * 4 + 2] += xv0 * w.z; acc[0][q * 4 + 3] += xv0 * w.w;
                    acc[1][q * 4 + 0] += xv1 * w.x; acc[1][q * 4 + 1] += xv1 * w.y;
                    acc[1][q * 4 + 2] += xv1 * w.z; acc[1][q * 4 + 3] += xv1 * w.w;
                }
            }
        }
        __syncthreads();   // drains DMA (vmcnt 0) + protects buffers
    }

    // main-phase smem dead -> stage Wes2 into smem[0..4095]
    float* We2 = smem;
    float* swl = smem + 4096;
#pragma unroll
    for (int i = 0; i < 4; ++i) {
        int f4 = i * 256 + tid;
        *(float4*)&We2[f4 * 4] = *(const float4*)(ws + WS_WES2 + f4 * 4);
    }

    // softmax per row (quad h=0..3 shares each row); write sw to out1 AND swl
    float colsum[16];
#pragma unroll
    for (int j = 0; j < 16; ++j) colsum[j] = 0.f;
#pragma unroll
    for (int i = 0; i < 2; ++i) {
        float mx = -1e30f;
#pragma unroll
        for (int j = 0; j < 16; ++j) {
            int m = h * 16 + j;
            acc[i][j] = (acc[i][j] + bcs[m]) * itxs[m];
            mx = fmaxf(mx, acc[i][j]);
        }
        mx = fmaxf(mx, __shfl_xor(mx, 1));
        mx = fmaxf(mx, __shfl_xor(mx, 2));
        float s = 0.f;
#pragma unroll
        for (int j = 0; j < 16; ++j) { acc[i][j] = __expf(acc[i][j] - mx); s += acc[i][j]; }
        s += __shfl_xor(s, 1);
        s += __shfl_xor(s, 2);
        float inv = 1.f / s;
        int rl = r + 64 * i;                 // local row 0..127
        int row = row0 + rl;
#pragma unroll
        for (int q = 0; q < 4; ++q) {
            float4 v = {acc[i][q * 4 + 0] * inv, acc[i][q * 4 + 1] * inv,
                        acc[i][q * 4 + 2] * inv, acc[i][q * 4 + 3] * inv};
            *(float4*)(out1 + (size_t)row * MM + h * 16 + q * 4) = v;
            *(float4*)&swl[rl * 68 + h * 16 + q * 4] = v;
#pragma unroll
            for (int j = 0; j < 4; ++j) colsum[q * 4 + j] += ((float*)&v)[j];
        }
    }
    // reduce colsum across the 16 r-lanes of each wave
#pragma unroll
    for (int j = 0; j < 16; ++j) {
        colsum[j] += __shfl_xor(colsum[j], 4);
        colsum[j] += __shfl_xor(colsum[j], 8);
        colsum[j] += __shfl_xor(colsum[j], 16);
        colsum[j] += __shfl_xor(colsum[j], 32);
    }
    if (lane < 4) {
#pragma unroll
        for (int j = 0; j < 16; ++j) redn[wv][h * 16 + j] = colsum[j];
    }

    // ---- fused es = sw @ Wes2, all operands from LDS (no shfl) ----
    __syncthreads();   // Wes2 + swl staged, redn written
    float es0[16], es1[16];
#pragma unroll
    for (int j = 0; j < 16; ++j) { es0[j] = 0.f; es1[j] = 0.f; }
#pragma unroll 8
    for (int k = 0; k < 64; ++k) {
        float a0 = swl[(r     ) * 68 + k];
        float a1 = swl[(r + 64) * 68 + k];
        const float4* wrow = (const float4*)&We2[k * 64 + h * 16];
#pragma unroll
        for (int j = 0; j < 4; ++j) {
            float4 wv4 = wrow[j];
            es0[j * 4 + 0] += a0 * wv4.x; es0[j * 4 + 1] += a0 * wv4.y;
            es0[j * 4 + 2] += a0 * wv4.z; es0[j * 4 + 3] += a0 * wv4.w;
            es1[j * 4 + 0] += a1 * wv4.x; es1[j * 4 + 1] += a1 * wv4.y;
            es1[j * 4 + 2] += a1 * wv4.z; es1[j * 4 + 3] += a1 * wv4.w;
        }
    }
    {
        size_t rowA = (size_t)(row0 + r) * MM + h * 16;
        size_t rowB = (size_t)(row0 + r + 64) * MM + h * 16;
        uint4 o;
        o.x = (unsigned int)f2bf(es0[0]) | ((unsigned int)f2bf(es0[1]) << 16);
        o.y = (unsigned int)f2bf(es0[2]) | ((unsigned int)f2bf(es0[3]) << 16);
        o.z = (unsigned int)f2bf(es0[4]) | ((unsigned int)f2bf(es0[5]) << 16);
        o.w = (unsigned int)f2bf(es0[6]) | ((unsigned int)f2bf(es0[7]) << 16);
        *(uint4*)(sw2b + rowA) = o;
        o.x = (unsigned int)f2bf(es0[8])  | ((unsigned int)f2bf(es0[9])  << 16);
        o.y = (unsigned int)f2bf(es0[10]) | ((unsigned int)f2bf(es0[11]) << 16);
        o.z = (unsigned int)f2bf(es0[12]) | ((unsigned int)f2bf(es0[13]) << 16);
        o.w = (unsigned int)f2bf(es0[14]) | ((unsigned int)f2bf(es0[15]) << 16);
        *(uint4*)(sw2b + rowA + 8) = o;
        o.x = (unsigned int)f2bf(es1[0]) | ((unsigned int)f2bf(es1[1]) << 16);
        o.y = (unsigned int)f2bf(es1[2]) | ((unsigned int)f2bf(es1[3]) << 16);
        o.z = (unsigned int)f2bf(es1[4]) | ((unsigned int)f2bf(es1[5]) << 16);
        o.w = (unsigned int)f2bf(es1[6]) | ((unsigned int)f2bf(es1[7]) << 16);
        *(uint4*)(sw2b + rowB) = o;
        o.x = (unsigned int)f2bf(es1[8])  | ((unsigned int)f2bf(es1[9])  << 16);
        o.y = (unsigned int)f2bf(es1[10]) | ((unsigned int)f2bf(es1[11]) << 16);
        o.z = (unsigned int)f2bf(es1[12]) | ((unsigned int)f2bf(es1[13]) << 16);
        o.w = (unsigned int)f2bf(es1[14]) | ((unsigned int)f2bf(es1[15]) << 16);
        *(uint4*)(sw2b + rowB + 8) = o;
    }

    if (tid < 64)
        atomicAdd(&norm_acc[b * MM + tid],
                  redn[0][tid] + redn[1][tid] + redn[2][tid] + redn[3][tid]);
#undef STAGE_CHUNK
}

// ---------- N2: Spart = sw_chunk^T @ x_chunk, C-split (r6 exact form, PB=64) ----------
__global__ __launch_bounds__(256, 2) void kN2(const float* __restrict__ x,
                                              const float* __restrict__ sw,
                                              float* __restrict__ Spart,
                                              int PB, int rowsPB) {
    __shared__ float xs[32][144];   // 18 KB, col j at j + (j>>5)*4 (2-way = free)
    __shared__ float sws[32][64];   // 8 KB
    const int bid = blockIdx.x;
    const int ch = bid & 1;
    const int p = (bid >> 1) % PB, b = (bid >> 1) / PB;
    const int base = b * NN + p * rowsPB;
    const int tid = threadIdx.x;
    const int tm = tid >> 4, tc = tid & 15;
    const int m0 = tm * 4;
    const int c0 = tc * 8;          // local col within the 128-wide half

    float acc[4][8];
#pragma unroll
    for (int mi = 0; mi < 4; ++mi)
#pragma unroll
        for (int j = 0; j < 8; ++j) acc[mi][j] = 0.f;

    for (int r0 = 0; r0 < rowsPB; r0 += 32) {
        __syncthreads();
#pragma unroll
        for (int i = 0; i < 4; ++i) {
            int flat = i * 256 + tid;
            int r = flat >> 5, c = (flat & 31) * 4;
            float4 v = *(const float4*)(x + (size_t)(base + r0 + r) * CC + ch * 128 + c);
            *(float4*)&xs[r][c + ((c >> 5) << 2)] = v;
        }
#pragma unroll
        for (int i = 0; i < 2; ++i) {
            int flat = i * 256 + tid;
            int r = flat >> 4, c = (flat & 15) * 4;
            *(float4*)&sws[r][c] = *(const float4*)(sw + (size_t)(base + r0 + r) * MM + c);
        }
        __syncthreads();
#pragma unroll 2
        for (int r = 0; r < 32; ++r) {
            float4 s4 = *(float4*)&sws[r][m0];
#pragma unroll
            for (int q = 0; q < 2; ++q) {
                int c = c0 + q * 4;
                float4 xv = *(float4*)&xs[r][c + ((c >> 5) << 2)];
                acc[0][q * 4 + 0] += s4.x * xv.x; acc[0][q * 4 + 1] += s4.x * xv.y;
                acc[0][q * 4 + 2] += s4.x * xv.z; acc[0][q * 4 + 3] += s4.x * xv.w;
                acc[1][q * 4 + 0] += s4.y * xv.x; acc[1][q * 4 + 1] += s4.y * xv.y;
                acc[1][q * 4 + 2] += s4.y * xv.z; acc[1][q * 4 + 3] += s4.y * xv.w;
                acc[2][q * 4 + 0] += s4.z * xv.x; acc[2][q * 4 + 1] += s4.z * xv.y;
                acc[2][q * 4 + 2] += s4.z * xv.z; acc[2][q * 4 + 3] += s4.z * xv.w;
                acc[3][q * 4 + 0] += s4.w * xv.x; acc[3][q * 4 + 1] += s4.w * xv.y;
                acc[3][q * 4 + 2] += s4.w * xv.z; acc[3][q * 4 + 3] += s4.w * xv.w;
            }
        }
    }
    float* dst = Spart + (size_t)(b * PB + p) * MM * CC + ch * 128;
#pragma unroll
    for (int mi = 0; mi < 4; ++mi)
#pragma unroll
        for (int q = 0; q < 2; ++q) {
            float4 v = {acc[mi][q * 4 + 0], acc[mi][q * 4 + 1],
                        acc[mi][q * 4 + 2], acc[mi][q * 4 + 3]};
            *(float4*)(dst + (size_t)(m0 + mi) * CC + c0 + q * 4) = v;
        }
}

// ---------- E: edge path: bf16 gather + softmax + two-pass transpose reduce ----------
__global__ __launch_bounds__(128, 4) void kE(const float* __restrict__ eattr,
                                             const int* __restrict__ eidx,
                                             const unsigned short* __restrict__ sw2b,
                                             const float* __restrict__ bes,
                                             float* __restrict__ t1_acc,
                                             float* __restrict__ esn_acc) {
    __shared__ float u[2][64][33];
    __shared__ float eav[2][64];
    __shared__ float redt[2][64], redn[2][64];
    __shared__ float bes_s[64];
    const int tid = threadIdx.x, w = tid >> 6, l = tid & 63;
    const int eg = blockIdx.x * 128 + tid;   // 262144 edges
    const int b = eg >> 16;
    if (tid < 64) bes_s[tid] = bes[tid];
    const int2 idx = ((const int2*)eidx)[eg];
    const float ea = eattr[eg];
    const uint4* g0 = (const uint4*)(sw2b + (size_t)(b * NN + idx.x) * MM);
    const uint4* g1 = (const uint4*)(sw2b + (size_t)(b * NN + idx.y) * MM);
    eav[w][l] = ea;
    __syncthreads();

    float v[64];
#pragma unroll
    for (int q = 0; q < 8; ++q) {
        uint4 a = g0[q], c = g1[q];
        unsigned int au[4] = {a.x, a.y, a.z, a.w};
        unsigned int cu[4] = {c.x, c.y, c.z, c.w};
#pragma unroll
        for (int j = 0; j < 4; ++j) {
            int m = q * 8 + j * 2;
            v[m + 0] = __uint_as_float(au[j] << 16) + __uint_as_float(cu[j] << 16) + bes_s[m + 0];
            v[m + 1] = __uint_as_float(au[j] & 0xFFFF0000u) + __uint_as_float(cu[j] & 0xFFFF0000u) + bes_s[m + 1];
        }
    }
    float mx = -1e30f;
#pragma unroll
    for (int m = 0; m < 64; ++m) mx = fmaxf(mx, v[m]);
    float s = 0.f;
#pragma unroll
    for (int m = 0; m < 64; ++m) { v[m] = __expf(v[m] - mx); s += v[m]; }
    float inv = 1.f / s;

    const int ml = l & 31, rh = l >> 5;
#pragma unroll
    for (int ph = 0; ph < 2; ++ph) {
        __syncthreads();   // previous phase reads done before overwrite
#pragma unroll
        for (int j = 0; j < 32; ++j) u[w][l][j] = v[ph * 32 + j] * inv;
        __syncthreads();
        float t = 0.f, n = 0.f;
#pragma unroll 8
        for (int rr = 0; rr < 32; ++rr) {
            int r = rh * 32 + rr;
            float e = u[w][r][ml];
            n += e;
            t += e * eav[w][r];
        }
        t += __shfl_xor(t, 32);
        n += __shfl_xor(n, 32);
        if (l < 32) { redt[w][ph * 32 + l] = t; redn[w][ph * 32 + l] = n; }
    }
    __syncthreads();
    if (tid < 64) {
        atomicAdd(&t1_acc[b * 64 + tid], redt[0][tid] + redt[1][tid]);
        atomicAdd(&esn_acc[b * 64 + tid], redn[0][tid] + redn[1][tid]);
    }
}

// ---------- R: parallel partial reduce Spart -> Ssum [B,M,C] ----------
__global__ __launch_bounds__(256) void kR(const float* __restrict__ Spart,
                                          float* __restrict__ Ssum, int PB) {
    const int idx = blockIdx.x * 256 + threadIdx.x;  // B*M*C = 262144
    const int b = idx >> 14;                          // M*C = 16384 per b
    const int mc = idx & 16383;
    const float* sp = Spart + (size_t)b * PB * MM * CC + mc;
    float a0 = 0.f, a1 = 0.f, a2 = 0.f, a3 = 0.f;
    for (int p = 0; p < PB; p += 4) {
        a0 += sp[(size_t)(p + 0) * MM * CC];
        a1 += sp[(size_t)(p + 1) * MM * CC];
        a2 += sp[(size_t)(p + 2) * MM * CC];
        a3 += sp[(size_t)(p + 3) * MM * CC];
    }
    Ssum[idx] = (a0 + a1) + (a2 + a3);
}

// ---------- F2: matvec + combine -> slice_token ----------
__global__ __launch_bounds__(256) void kF2(const float* __restrict__ ws,
                                           const float* __restrict__ Wfx,
                                           const float* __restrict__ bfx,
                                           const float* __restrict__ Wfe,
                                           const float* __restrict__ bfe,
                                           const float* __restrict__ phe,
                                           float* __restrict__ out0) {
    __shared__ float srow[256];
    const int bid = blockIdx.x;          // 256 blocks = (b,m)
    const int b = bid >> 6, m = bid & 63;
    const int t = threadIdx.x;
    srow[t] = ws[WS_SSUM + (size_t)(b * MM + m) * CC + t];
    __syncthreads();
    float acc = 0.f;
#pragma unroll 8
    for (int k = 0; k < 256; ++k) acc += srow[k] * Wfx[k * CC + t];
    float nv  = ws[WS_NORM + b * 64 + m];
    float t1v = ws[WS_T1   + b * 64 + m];
    float ev  = ws[WS_ESN  + b * 64 + m];
    const float scale = (float)NN / (float)EE;   // 0.25
    float num = acc + nv * bfx[t] + scale * (t1v * Wfe[t] + ev * (bfe[t] + phe[t]));
    float den = nv + scale * ev + 1e-5f;
    out0[(size_t)(b * MM + m) * CC + t] = num / den;
}

extern "C" void kernel_launch(void* const* d_in, const int* in_sizes, int n_in,
                              void* d_out, int out_size, void* d_ws, size_t ws_size,
                              hipStream_t stream) {
    const float* x     = (const float*)d_in[0];
    const float* eattr = (const float*)d_in[1];
    const int*   eidx  = (const int*)d_in[2];
    const float* Wfx   = (const float*)d_in[3];
    const float* bfx   = (const float*)d_in[4];
    const float* Wx    = (const float*)d_in[5];
    const float* bx    = (const float*)d_in[6];
    const float* Wsl   = (const float*)d_in[7];
    const float* bsl   = (const float*)d_in[8];
    const float* tx    = (const float*)d_in[9];
    const float* phx   = (const float*)d_in[10];
    const float* Wfe   = (const float*)d_in[11];
    const float* bfe   = (const float*)d_in[12];
    const float* te    = (const float*)d_in[13];
    const float* Wes   = (const float*)d_in[14];
    const float* bes   = (const float*)d_in[15];
    const float* phe   = (const float*)d_in[16];

    float* out0 = (float*)d_out;                  // slice_token [B,M,C]
    float* out1 = out0 + (size_t)BB * MM * CC;    // slice_weight [B,N,M]
    float* ws   = (float*)d_ws;
    unsigned short* sw2b = (unsigned short*)(ws + WS_SW2);

    int PB = 64;
    while (PB > 8) {
        size_t need = (size_t)(WS_SPART + (size_t)BB * PB * MM * CC) * sizeof(float);
        if (need <= ws_size) break;
        PB >>= 1;
    }
    int rowsPB = NN / PB;

    hipMemsetAsync(ws, 0, 768 * sizeof(float), stream);

    kP <<<64, 256, 0, stream>>>(Wx, Wsl, ws);
    kP2<<<1, 64, 0, stream>>>(bx, phx, Wsl, bsl, tx, te, Wes, ws);
    kN1<<<512, 256, 0, stream>>>(x, ws, out1, sw2b, ws + WS_NORM);
    kE <<<2048, 128, 0, stream>>>(eattr, eidx, sw2b, bes,
                                  ws + WS_T1, ws + WS_ESN);
    kN2<<<BB * PB * 2, 256, 0, stream>>>(x, out1, ws + WS_SPART, PB, rowsPB);
    kR <<<1024, 256, 0, stream>>>(ws + WS_SPART, ws + WS_SSUM, PB);
    kF2<<<256, 256, 0, stream>>>(ws, Wfx, bfx, Wfe, bfe, phe, out0);
}

// Round 14
// 153.391 us; speedup vs baseline: 1.1939x; 1.1939x over previous
//
#include <hip/hip_runtime.h>

#define BB 4
#define NN 16384
#define EE 65536
#define CC 256
#define MM 64

// ws float offsets
#define WS_NORM   0                  // B*M (atomics, memset each launch)
#define WS_T1     256
#define WS_ESN    512
#define WS_BCOMB  768                // 64
#define WS_ITX    832                // 64
#define WS_ITE    896                // 64
#define WS_WES2   1024               // 64*64 = 4096  (itE ⊙ W_eslice)
#define WS_WCOMB  5120               // C*M = 16384
#define WS_SW2    21504              // bf16 SW2 [B*N*M ushorts] lives here (8MB);
#define WS_SSUM   WS_SW2             // after kE, overlaid by Ssum [B*M*C floats]
#define WS_SPART  4215808            // B*PB*M*C partials

static __device__ __forceinline__ unsigned short f2bf(float f) {
    unsigned int u = __float_as_uint(f);
    unsigned int r = (u + 0x7FFFu + ((u >> 16) & 1u)) >> 16;   // RNE
    return (unsigned short)r;
}

// ---------- PP: merged preamble. Blocks 0..255: W_comb row c. Block 256: b_comb etc.
// r14: old kP was 64 blocks w/ serial 256-iter loops (1 block per 4 CUs); old kP2
// was ONE 64-thread block — both latency-bound on the critical chain. Now: one
// block per output row, 4 waves split K, coalesced Wsl reads, LDS reduce.
__global__ __launch_bounds__(256) void kPP(const float* __restrict__ Wx,
                                           const float* __restrict__ Wsl,
                                           const float* __restrict__ bx,
                                           const float* __restrict__ phx,
                                           const float* __restrict__ bsl,
                                           const float* __restrict__ tx,
                                           const float* __restrict__ te,
                                           const float* __restrict__ Wes,
                                           float* __restrict__ ws) {
    __shared__ float row[256];
    __shared__ float part[4][64];
    const int tid = threadIdx.x;
    const int m = tid & 63, kq = tid >> 6;
    if (blockIdx.x < 256) {
        const int c = blockIdx.x;
        row[tid] = Wx[c * CC + tid];
        __syncthreads();
        float acc = 0.f;
#pragma unroll 8
        for (int kk = 0; kk < 64; ++kk) {
            int k = kq * 64 + kk;
            acc += row[k] * Wsl[k * MM + m];
        }
        part[kq][m] = acc;
        __syncthreads();
        if (tid < 64)
            ws[WS_WCOMB + c * MM + tid] =
                part[0][tid] + part[1][tid] + part[2][tid] + part[3][tid];
    } else {
        row[tid] = bx[tid] + phx[tid];
        __syncthreads();
        float acc = 0.f;
#pragma unroll 8
        for (int kk = 0; kk < 64; ++kk) {
            int k = kq * 64 + kk;
            acc += row[k] * Wsl[k * MM + m];
        }
        part[kq][m] = acc;
        __syncthreads();
        if (tid < 64) {
            ws[WS_BCOMB + tid] = bsl[tid] +
                part[0][tid] + part[1][tid] + part[2][tid] + part[3][tid];
            ws[WS_ITX + tid] = 1.f / fminf(fmaxf(tx[tid], 0.01f), 5.f);
            ws[WS_ITE + tid] = 1.f / fminf(fmaxf(te[tid], 0.01f), 5.f);
        }
#pragma unroll
        for (int i = 0; i < 16; ++i) {
            int e = i * 256 + tid;
            int k = e >> 6;
            float itk = 1.f / fminf(fmaxf(te[k], 0.01f), 5.f);
            ws[WS_WES2 + e] = itk * Wes[e];
        }
    }
}

// ---------- N1: x@W_comb -> softmax -> sw (out1) + norm + fused sw@Wes2 -> sw2b ----------
// EXACT r12 form (68.6us best known). r13's global_load_lds staging regressed to
// 85us (barrier still drains vmcnt(0); DMA adds LDS-write contention) — reverted.
__global__ __launch_bounds__(256, 2) void kN1(const float* __restrict__ x,
                                              const float* __restrict__ ws,
                                              float* __restrict__ out1,
                                              unsigned short* __restrict__ sw2b,
                                              float* __restrict__ norm_acc) {
    // union: main phase: xs = smem[0..4607] (128x36), Wst = smem[4608..6655] (32x64)
    //        epilogue:  Wes2 = smem[0..4095] (64x64), swl = smem[4096..12799] (128x68)
    __shared__ float smem[12800];    // 51.2 KB
    __shared__ float redn[4][64];
    __shared__ float bcs[64], itxs[64];
    float* xs  = smem;
    float* Wst = smem + 4608;
    float* We2 = smem;
    float* swl = smem + 4096;
    const int tid = threadIdx.x;
    const int row0 = blockIdx.x * 128;
    const int b = blockIdx.x >> 7;   // 128 blocks per batch
    const int r = tid >> 2;          // 0..63 (rows r and r+64)
    const int h = tid & 3;           // m-quarter
    const float* Wc = ws + WS_WCOMB;

    if (tid < 64) { bcs[tid] = ws[WS_BCOMB + tid]; itxs[tid] = ws[WS_ITX + tid]; }

    float acc[2][16];
#pragma unroll
    for (int i = 0; i < 2; ++i)
#pragma unroll
        for (int j = 0; j < 16; ++j) acc[i][j] = 0.f;

    for (int c0 = 0; c0 < CC; c0 += 32) {
        __syncthreads();
#pragma unroll
        for (int i = 0; i < 4; ++i) {
            int flat = i * 256 + tid, rr = flat >> 3, cb = (flat & 7) * 4;
            float4 v = *(const float4*)(x + (size_t)(row0 + rr) * CC + c0 + cb);
            *(float4*)&xs[rr * 36 + cb] = v;
        }
#pragma unroll
        for (int i = 0; i < 2; ++i) {
            int f4 = i * 256 + tid;
            *(float4*)&Wst[f4 * 4] = *(const float4*)(Wc + c0 * MM + f4 * 4);
        }
        __syncthreads();
#pragma unroll
        for (int cc4 = 0; cc4 < 8; ++cc4) {
            float4 a0 = *(float4*)&xs[(r     ) * 36 + cc4 * 4];
            float4 a1 = *(float4*)&xs[(r + 64) * 36 + cc4 * 4];
            float av0[4] = {a0.x, a0.y, a0.z, a0.w};
            float av1[4] = {a1.x, a1.y, a1.z, a1.w};
#pragma unroll
            for (int k = 0; k < 4; ++k) {
                float xv0 = av0[k], xv1 = av1[k];
                const float4* wrow = (const float4*)&Wst[(cc4 * 4 + k) * 64 + h * 16];
#pragma unroll
                for (int q = 0; q < 4; ++q) {
                    float4 w = wrow[q];
                    acc[0][q * 4 + 0] += xv0 * w.x; acc[0][q * 4 + 1] += xv0 * w.y;
                    acc[0][q * 4 + 2] += xv0 * w.z; acc[0][q * 4 + 3] += xv0 * w.w;
                    acc[1][q * 4 + 0] += xv1 * w.x; acc[1][q * 4 + 1] += xv1 * w.y;
                    acc[1][q * 4 + 2] += xv1 * w.z; acc[1][q * 4 + 3] += xv1 * w.w;
                }
            }
        }
    }

    // main-phase smem dead -> stage Wes2 into smem[0..4095]
    __syncthreads();
#pragma unroll
    for (int i = 0; i < 4; ++i) {
        int f4 = i * 256 + tid;
        *(float4*)&We2[f4 * 4] = *(const float4*)(ws + WS_WES2 + f4 * 4);
    }

    // softmax per row (quad h=0..3 shares each row); write sw to out1 AND swl
    float colsum[16];
#pragma unroll
    for (int j = 0; j < 16; ++j) colsum[j] = 0.f;
#pragma unroll
    for (int i = 0; i < 2; ++i) {
        float mx = -1e30f;
#pragma unroll
        for (int j = 0; j < 16; ++j) {
            int m = h * 16 + j;
            acc[i][j] = (acc[i][j] + bcs[m]) * itxs[m];
            mx = fmaxf(mx, acc[i][j]);
        }
        mx = fmaxf(mx, __shfl_xor(mx, 1));
        mx = fmaxf(mx, __shfl_xor(mx, 2));
        float s = 0.f;
#pragma unroll
        for (int j = 0; j < 16; ++j) { acc[i][j] = __expf(acc[i][j] - mx); s += acc[i][j]; }
        s += __shfl_xor(s, 1);
        s += __shfl_xor(s, 2);
        float inv = 1.f / s;
        int rl = r + 64 * i;                 // local row 0..127
        int row = row0 + rl;
#pragma unroll
        for (int q = 0; q < 4; ++q) {
            float4 v = {acc[i][q * 4 + 0] * inv, acc[i][q * 4 + 1] * inv,
                        acc[i][q * 4 + 2] * inv, acc[i][q * 4 + 3] * inv};
            *(float4*)(out1 + (size_t)row * MM + h * 16 + q * 4) = v;
            *(float4*)&swl[rl * 68 + h * 16 + q * 4] = v;
#pragma unroll
            for (int j = 0; j < 4; ++j) colsum[q * 4 + j] += ((float*)&v)[j];
        }
    }
    // reduce colsum across the 16 r-lanes of each wave
#pragma unroll
    for (int j = 0; j < 16; ++j) {
        colsum[j] += __shfl_xor(colsum[j], 4);
        colsum[j] += __shfl_xor(colsum[j], 8);
        colsum[j] += __shfl_xor(colsum[j], 16);
        colsum[j] += __shfl_xor(colsum[j], 32);
    }
    int w = tid >> 6;
    if ((tid & 63) < 4) {
#pragma unroll
        for (int j = 0; j < 16; ++j) redn[w][h * 16 + j] = colsum[j];
    }

    // ---- fused es = sw @ Wes2, all operands from LDS (no shfl) ----
    __syncthreads();   // Wes2 + swl staged, redn written
    float es0[16], es1[16];
#pragma unroll
    for (int j = 0; j < 16; ++j) { es0[j] = 0.f; es1[j] = 0.f; }
#pragma unroll 8
    for (int k = 0; k < 64; ++k) {
        float a0 = swl[(r     ) * 68 + k];
        float a1 = swl[(r + 64) * 68 + k];
        const float4* wrow = (const float4*)&We2[k * 64 + h * 16];
#pragma unroll
        for (int j = 0; j < 4; ++j) {
            float4 wv = wrow[j];
            es0[j * 4 + 0] += a0 * wv.x; es0[j * 4 + 1] += a0 * wv.y;
            es0[j * 4 + 2] += a0 * wv.z; es0[j * 4 + 3] += a0 * wv.w;
            es1[j * 4 + 0] += a1 * wv.x; es1[j * 4 + 1] += a1 * wv.y;
            es1[j * 4 + 2] += a1 * wv.z; es1[j * 4 + 3] += a1 * wv.w;
        }
    }
    {
        size_t rowA = (size_t)(row0 + r) * MM + h * 16;
        size_t rowB = (size_t)(row0 + r + 64) * MM + h * 16;
        uint4 o;
        o.x = (unsigned int)f2bf(es0[0]) | ((unsigned int)f2bf(es0[1]) << 16);
        o.y = (unsigned int)f2bf(es0[2]) | ((unsigned int)f2bf(es0[3]) << 16);
        o.z = (unsigned int)f2bf(es0[4]) | ((unsigned int)f2bf(es0[5]) << 16);
        o.w = (unsigned int)f2bf(es0[6]) | ((unsigned int)f2bf(es0[7]) << 16);
        *(uint4*)(sw2b + rowA) = o;
        o.x = (unsigned int)f2bf(es0[8])  | ((unsigned int)f2bf(es0[9])  << 16);
        o.y = (unsigned int)f2bf(es0[10]) | ((unsigned int)f2bf(es0[11]) << 16);
        o.z = (unsigned int)f2bf(es0[12]) | ((unsigned int)f2bf(es0[13]) << 16);
        o.w = (unsigned int)f2bf(es0[14]) | ((unsigned int)f2bf(es0[15]) << 16);
        *(uint4*)(sw2b + rowA + 8) = o;
        o.x = (unsigned int)f2bf(es1[0]) | ((unsigned int)f2bf(es1[1]) << 16);
        o.y = (unsigned int)f2bf(es1[2]) | ((unsigned int)f2bf(es1[3]) << 16);
        o.z = (unsigned int)f2bf(es1[4]) | ((unsigned int)f2bf(es1[5]) << 16);
        o.w = (unsigned int)f2bf(es1[6]) | ((unsigned int)f2bf(es1[7]) << 16);
        *(uint4*)(sw2b + rowB) = o;
        o.x = (unsigned int)f2bf(es1[8])  | ((unsigned int)f2bf(es1[9])  << 16);
        o.y = (unsigned int)f2bf(es1[10]) | ((unsigned int)f2bf(es1[11]) << 16);
        o.z = (unsigned int)f2bf(es1[12]) | ((unsigned int)f2bf(es1[13]) << 16);
        o.w = (unsigned int)f2bf(es1[14]) | ((unsigned int)f2bf(es1[15]) << 16);
        *(uint4*)(sw2b + rowB + 8) = o;
    }

    if (tid < 64)
        atomicAdd(&norm_acc[b * MM + tid],
                  redn[0][tid] + redn[1][tid] + redn[2][tid] + redn[3][tid]);
}

// ---------- N2: Spart = sw_chunk^T @ x_chunk, C-split (r6 exact form, PB=64) ----------
__global__ __launch_bounds__(256, 2) void kN2(const float* __restrict__ x,
                                              const float* __restrict__ sw,
                                              float* __restrict__ Spart,
                                              int PB, int rowsPB) {
    __shared__ float xs[32][144];   // 18 KB, col j at j + (j>>5)*4 (2-way = free)
    __shared__ float sws[32][64];   // 8 KB
    const int bid = blockIdx.x;
    const int ch = bid & 1;
    const int p = (bid >> 1) % PB, b = (bid >> 1) / PB;
    const int base = b * NN + p * rowsPB;
    const int tid = threadIdx.x;
    const int tm = tid >> 4, tc = tid & 15;
    const int m0 = tm * 4;
    const int c0 = tc * 8;          // local col within the 128-wide half

    float acc[4][8];
#pragma unroll
    for (int mi = 0; mi < 4; ++mi)
#pragma unroll
        for (int j = 0; j < 8; ++j) acc[mi][j] = 0.f;

    for (int r0 = 0; r0 < rowsPB; r0 += 32) {
        __syncthreads();
#pragma unroll
        for (int i = 0; i < 4; ++i) {
            int flat = i * 256 + tid;
            int r = flat >> 5, c = (flat & 31) * 4;
            float4 v = *(const float4*)(x + (size_t)(base + r0 + r) * CC + ch * 128 + c);
            *(float4*)&xs[r][c + ((c >> 5) << 2)] = v;
        }
#pragma unroll
        for (int i = 0; i < 2; ++i) {
            int flat = i * 256 + tid;
            int r = flat >> 4, c = (flat & 15) * 4;
            *(float4*)&sws[r][c] = *(const float4*)(sw + (size_t)(base + r0 + r) * MM + c);
        }
        __syncthreads();
#pragma unroll 2
        for (int r = 0; r < 32; ++r) {
            float4 s4 = *(float4*)&sws[r][m0];
#pragma unroll
            for (int q = 0; q < 2; ++q) {
                int c = c0 + q * 4;
                float4 xv = *(float4*)&xs[r][c + ((c >> 5) << 2)];
                acc[0][q * 4 + 0] += s4.x * xv.x; acc[0][q * 4 + 1] += s4.x * xv.y;
                acc[0][q * 4 + 2] += s4.x * xv.z; acc[0][q * 4 + 3] += s4.x * xv.w;
                acc[1][q * 4 + 0] += s4.y * xv.x; acc[1][q * 4 + 1] += s4.y * xv.y;
                acc[1][q * 4 + 2] += s4.y * xv.z; acc[1][q * 4 + 3] += s4.y * xv.w;
                acc[2][q * 4 + 0] += s4.z * xv.x; acc[2][q * 4 + 1] += s4.z * xv.y;
                acc[2][q * 4 + 2] += s4.z * xv.z; acc[2][q * 4 + 3] += s4.z * xv.w;
                acc[3][q * 4 + 0] += s4.w * xv.x; acc[3][q * 4 + 1] += s4.w * xv.y;
                acc[3][q * 4 + 2] += s4.w * xv.z; acc[3][q * 4 + 3] += s4.w * xv.w;
            }
        }
    }
    float* dst = Spart + (size_t)(b * PB + p) * MM * CC + ch * 128;
#pragma unroll
    for (int mi = 0; mi < 4; ++mi)
#pragma unroll
        for (int q = 0; q < 2; ++q) {
            float4 v = {acc[mi][q * 4 + 0], acc[mi][q * 4 + 1],
                        acc[mi][q * 4 + 2], acc[mi][q * 4 + 3]};
            *(float4*)(dst + (size_t)(m0 + mi) * CC + c0 + q * 4) = v;
        }
}

// ---------- E: edge path: bf16 gather + softmax + two-pass transpose reduce ----------
__global__ __launch_bounds__(128, 4) void kE(const float* __restrict__ eattr,
                                             const int* __restrict__ eidx,
                                             const unsigned short* __restrict__ sw2b,
                                             const float* __restrict__ bes,
                                             float* __restrict__ t1_acc,
                                             float* __restrict__ esn_acc) {
    __shared__ float u[2][64][33];
    __shared__ float eav[2][64];
    __shared__ float redt[2][64], redn[2][64];
    __shared__ float bes_s[64];
    const int tid = threadIdx.x, w = tid >> 6, l = tid & 63;
    const int eg = blockIdx.x * 128 + tid;   // 262144 edges
    const int b = eg >> 16;
    if (tid < 64) bes_s[tid] = bes[tid];
    const int2 idx = ((const int2*)eidx)[eg];
    const float ea = eattr[eg];
    const uint4* g0 = (const uint4*)(sw2b + (size_t)(b * NN + idx.x) * MM);
    const uint4* g1 = (const uint4*)(sw2b + (size_t)(b * NN + idx.y) * MM);
    eav[w][l] = ea;
    __syncthreads();

    float v[64];
#pragma unroll
    for (int q = 0; q < 8; ++q) {
        uint4 a = g0[q], c = g1[q];
        unsigned int au[4] = {a.x, a.y, a.z, a.w};
        unsigned int cu[4] = {c.x, c.y, c.z, c.w};
#pragma unroll
        for (int j = 0; j < 4; ++j) {
            int m = q * 8 + j * 2;
            v[m + 0] = __uint_as_float(au[j] << 16) + __uint_as_float(cu[j] << 16) + bes_s[m + 0];
            v[m + 1] = __uint_as_float(au[j] & 0xFFFF0000u) + __uint_as_float(cu[j] & 0xFFFF0000u) + bes_s[m + 1];
        }
    }
    float mx = -1e30f;
#pragma unroll
    for (int m = 0; m < 64; ++m) mx = fmaxf(mx, v[m]);
    float s = 0.f;
#pragma unroll
    for (int m = 0; m < 64; ++m) { v[m] = __expf(v[m] - mx); s += v[m]; }
    float inv = 1.f / s;

    const int ml = l & 31, rh = l >> 5;
#pragma unroll
    for (int ph = 0; ph < 2; ++ph) {
        __syncthreads();   // previous phase reads done before overwrite
#pragma unroll
        for (int j = 0; j < 32; ++j) u[w][l][j] = v[ph * 32 + j] * inv;
        __syncthreads();
        float t = 0.f, n = 0.f;
#pragma unroll 8
        for (int rr = 0; rr < 32; ++rr) {
            int r = rh * 32 + rr;
            float e = u[w][r][ml];
            n += e;
            t += e * eav[w][r];
        }
        t += __shfl_xor(t, 32);
        n += __shfl_xor(n, 32);
        if (l < 32) { redt[w][ph * 32 + l] = t; redn[w][ph * 32 + l] = n; }
    }
    __syncthreads();
    if (tid < 64) {
        atomicAdd(&t1_acc[b * 64 + tid], redt[0][tid] + redt[1][tid]);
        atomicAdd(&esn_acc[b * 64 + tid], redn[0][tid] + redn[1][tid]);
    }
}

// ---------- R: parallel partial reduce Spart -> Ssum [B,M,C] ----------
__global__ __launch_bounds__(256) void kR(const float* __restrict__ Spart,
                                          float* __restrict__ Ssum, int PB) {
    const int idx = blockIdx.x * 256 + threadIdx.x;  // B*M*C = 262144
    const int b = idx >> 14;                          // M*C = 16384 per b
    const int mc = idx & 16383;
    const float* sp = Spart + (size_t)b * PB * MM * CC + mc;
    float a0 = 0.f, a1 = 0.f, a2 = 0.f, a3 = 0.f;
    for (int p = 0; p < PB; p += 4) {
        a0 += sp[(size_t)(p + 0) * MM * CC];
        a1 += sp[(size_t)(p + 1) * MM * CC];
        a2 += sp[(size_t)(p + 2) * MM * CC];
        a3 += sp[(size_t)(p + 3) * MM * CC];
    }
    Ssum[idx] = (a0 + a1) + (a2 + a3);
}

// ---------- F2: matvec + combine -> slice_token ----------
__global__ __launch_bounds__(256) void kF2(const float* __restrict__ ws,
                                           const float* __restrict__ Wfx,
                                           const float* __restrict__ bfx,
                                           const float* __restrict__ Wfe,
                                           const float* __restrict__ bfe,
                                           const float* __restrict__ phe,
                                           float* __restrict__ out0) {
    __shared__ float srow[256];
    const int bid = blockIdx.x;          // 256 blocks = (b,m)
    const int b = bid >> 6, m = bid & 63;
    const int t = threadIdx.x;
    srow[t] = ws[WS_SSUM + (size_t)(b * MM + m) * CC + t];
    __syncthreads();
    float acc = 0.f;
#pragma unroll 8
    for (int k = 0; k < 256; ++k) acc += srow[k] * Wfx[k * CC + t];
    float nv  = ws[WS_NORM + b * 64 + m];
    float t1v = ws[WS_T1   + b * 64 + m];
    float ev  = ws[WS_ESN  + b * 64 + m];
    const float scale = (float)NN / (float)EE;   // 0.25
    float num = acc + nv * bfx[t] + scale * (t1v * Wfe[t] + ev * (bfe[t] + phe[t]));
    float den = nv + scale * ev + 1e-5f;
    out0[(size_t)(b * MM + m) * CC + t] = num / den;
}

extern "C" void kernel_launch(void* const* d_in, const int* in_sizes, int n_in,
                              void* d_out, int out_size, void* d_ws, size_t ws_size,
                              hipStream_t stream) {
    const float* x     = (const float*)d_in[0];
    const float* eattr = (const float*)d_in[1];
    const int*   eidx  = (const int*)d_in[2];
    const float* Wfx   = (const float*)d_in[3];
    const float* bfx   = (const float*)d_in[4];
    const float* Wx    = (const float*)d_in[5];
    const float* bx    = (const float*)d_in[6];
    const float* Wsl   = (const float*)d_in[7];
    const float* bsl   = (const float*)d_in[8];
    const float* tx    = (const float*)d_in[9];
    const float* phx   = (const float*)d_in[10];
    const float* Wfe   = (const float*)d_in[11];
    const float* bfe   = (const float*)d_in[12];
    const float* te    = (const float*)d_in[13];
    const float* Wes   = (const float*)d_in[14];
    const float* bes   = (const float*)d_in[15];
    const float* phe   = (const float*)d_in[16];

    float* out0 = (float*)d_out;                  // slice_token [B,M,C]
    float* out1 = out0 + (size_t)BB * MM * CC;    // slice_weight [B,N,M]
    float* ws   = (float*)d_ws;
    unsigned short* sw2b = (unsigned short*)(ws + WS_SW2);

    int PB = 64;
    while (PB > 8) {
        size_t need = (size_t)(WS_SPART + (size_t)BB * PB * MM * CC) * sizeof(float);
        if (need <= ws_size) break;
        PB >>= 1;
    }
    int rowsPB = NN / PB;

    hipMemsetAsync(ws, 0, 768 * sizeof(float), stream);

    kPP<<<257, 256, 0, stream>>>(Wx, Wsl, bx, phx, bsl, tx, te, Wes, ws);
    kN1<<<512, 256, 0, stream>>>(x, ws, out1, sw2b, ws + WS_NORM);
    kE <<<2048, 128, 0, stream>>>(eattr, eidx, sw2b, bes,
                                  ws + WS_T1, ws + WS_ESN);
    kN2<<<BB * PB * 2, 256, 0, stream>>>(x, out1, ws + WS_SPART, PB, rowsPB);
    kR <<<1024, 256, 0, stream>>>(ws + WS_SPART, ws + WS_SSUM, PB);
    kF2<<<256, 256, 0, stream>>>(ws, Wfx, bfx, Wfe, bfe, phe, out0);
}